// Round 12
// baseline (4096.722 us; speedup 1.0000x reference)
//
#include <hip/hip_runtime.h>
#include <hip/hip_bf16.h>

// ---------------------------------------------------------------------------
// KiperwasserDependencyParser: embed -> bi-LSTM x2 -> pairwise MLP -> softmax
// Round 12: dual-dir scan, 2 barriers/step (producer-self-sufficient gates,
// xw loads moved into producer), sleep-staggered sub-RT poll sampling.
// ---------------------------------------------------------------------------

#define L2E 1.4426950408889634f

__device__ __forceinline__ float fast_rcp(float x) { return __builtin_amdgcn_rcpf(x); }
__device__ __forceinline__ float sigm_f(float x) {
    return fast_rcp(1.f + exp2f(-x * L2E));
}
__device__ __forceinline__ float tanh_f(float x) {
    return 1.f - 2.f * fast_rcp(1.f + exp2f(x * (2.f * L2E)));
}

// publish tagged 8B message to the coherence point (R10/R11-proven).
__device__ __forceinline__ void st_msg(unsigned long long* p, unsigned long long m) {
    asm volatile("global_store_dwordx2 %0, %1, off sc0 sc1"
                 :: "v"(p), "v"(m) : "memory");
}

// 4-deep poll with s_sleep-staggered issues (~192cy apart) -> detect samples
// every ~200-370cy instead of once per RT. Bounded; falls back to the proven
// relaxed-agent loop. Wave-uniform exit via __all.
__device__ __forceinline__ unsigned long long poll_msg(
    const unsigned long long* p, unsigned want)
{
    unsigned long long r0, r1, r2, r3, r = 0;
    bool done = false;
    for (int it = 0; it < 4096 && !done; ++it) {
        asm volatile(
            "global_load_dwordx2 %0, %4, off sc0 sc1\n\t"
            "s_sleep 3\n\t"
            "global_load_dwordx2 %1, %4, off sc0 sc1\n\t"
            "s_sleep 3\n\t"
            "global_load_dwordx2 %2, %4, off sc0 sc1\n\t"
            "s_sleep 3\n\t"
            "global_load_dwordx2 %3, %4, off sc0 sc1\n\t"
            "s_waitcnt vmcnt(3)"
            : "=&v"(r0), "=&v"(r1), "=&v"(r2), "=&v"(r3)
            : "v"(p) : "memory");
        if (__all((unsigned)(r0 >> 32) == want)) { r = r0; done = true; }
        if (!done) {
            asm volatile("s_waitcnt vmcnt(2)" ::: "memory");
            if (__all((unsigned)(r1 >> 32) == want)) { r = r1; done = true; }
        }
        if (!done) {
            asm volatile("s_waitcnt vmcnt(1)" ::: "memory");
            if (__all((unsigned)(r2 >> 32) == want)) { r = r2; done = true; }
        }
        if (!done) {
            asm volatile("s_waitcnt vmcnt(0)" ::: "memory");
            if (__all((unsigned)(r3 >> 32) == want)) { r = r3; done = true; }
        }
        asm volatile("s_waitcnt vmcnt(0)" ::: "memory");  // drain in-flight
    }
    if (!done) {   // guaranteed-terminating proven path
        do {
            r = __hip_atomic_load(p, __ATOMIC_RELAXED, __HIP_MEMORY_SCOPE_AGENT);
        } while (!__all((unsigned)(r >> 32) == want));
    }
    return r;
}

// ----------------------------- embed ---------------------------------------
__global__ __launch_bounds__(256) void embed_kernel(
    const float* __restrict__ wt, const float* __restrict__ pt,
    const int* __restrict__ wi, const int* __restrict__ pi,
    float* __restrict__ x)
{
    int idx = blockIdx.x * 256 + threadIdx.x;
    if (idx >= 1024 * 576) return;
    int n = idx / 576, c = idx % 576;
    x[idx] = (c < 512) ? wt[wi[n] * 512 + c] : pt[pi[n] * 64 + (c - 512)];
}

// --------------------------- GEMM + bias ------------------------------------
__global__ __launch_bounds__(256) void gemm_bias(
    const float* __restrict__ A,
    const float* __restrict__ W0, const float* __restrict__ W1,
    const float* __restrict__ b0, const float* __restrict__ b1,
    float* __restrict__ C0, float* __restrict__ C1,
    int M, int N, int K)
{
    const float* W = blockIdx.z ? W1 : W0;
    const float* bias = blockIdx.z ? b1 : b0;
    float* C = blockIdx.z ? C1 : C0;
    int m0 = blockIdx.y * 64, n0 = blockIdx.x * 64;
    __shared__ float As[16][65];
    __shared__ float Ws[16][65];
    int tid = threadIdx.x;
    int tx = tid & 15, ty = tid >> 4;
    float acc[4][4] = {};
    int lr = tid >> 2, lkc = (tid & 3) * 4;
    for (int k0 = 0; k0 < K; k0 += 16) {
        float4 a4 = *(const float4*)&A[(size_t)(m0 + lr) * K + k0 + lkc];
        float4 w4 = *(const float4*)&W[(size_t)(n0 + lr) * K + k0 + lkc];
        As[lkc + 0][lr] = a4.x; As[lkc + 1][lr] = a4.y;
        As[lkc + 2][lr] = a4.z; As[lkc + 3][lr] = a4.w;
        Ws[lkc + 0][lr] = w4.x; Ws[lkc + 1][lr] = w4.y;
        Ws[lkc + 2][lr] = w4.z; Ws[lkc + 3][lr] = w4.w;
        __syncthreads();
#pragma unroll
        for (int k = 0; k < 16; k++) {
            float a[4], b[4];
#pragma unroll
            for (int i = 0; i < 4; i++) a[i] = As[k][ty * 4 + i];
#pragma unroll
            for (int j = 0; j < 4; j++) b[j] = Ws[k][tx * 4 + j];
#pragma unroll
            for (int i = 0; i < 4; i++)
#pragma unroll
                for (int j = 0; j < 4; j++) acc[i][j] += a[i] * b[j];
        }
        __syncthreads();
    }
    int colbase = n0 + tx * 4;
    float4 bv = *(const float4*)&bias[colbase];
#pragma unroll
    for (int i = 0; i < 4; i++) {
        float4 o;
        o.x = acc[i][0] + bv.x; o.y = acc[i][1] + bv.y;
        o.z = acc[i][2] + bv.z; o.w = acc[i][3] + bv.w;
        *(float4*)&C[(size_t)(m0 + ty * 4 + i) * N + colbase] = o;
    }
}

// ----------------------------- LSTM scan ------------------------------------
// 8 blocks; block `sub` owns h[32*sub..32*sub+32) of BOTH directions.
// Threads 0-255 dot dir0, 256-511 dot dir1 (128 rows x 2 k-halves each).
// Producers: wave 0 lanes 0-31 (dir0), wave 4 lanes 0-31 (dir1). Each
// producer lane is SELF-SUFFICIENT: loads its 4 xw values at loop top
// (complete during dot), reads its 8 partials after B1, does 4 activations
// + c/h + publish. Waves 1-7 poll one remote producer's combined slot.
// 2 barriers/step. Messaging primitives proven in R10/R11.
__global__ __launch_bounds__(512, 2) void lstm_scan(
    const float* __restrict__ xw_f, const float* __restrict__ xw_b,
    const float* __restrict__ Whh_f, const float* __restrict__ Whh_b,
    float* __restrict__ hout,              // [1024][512]
    unsigned long long* __restrict__ hx)   // [prod 8][par 2][64] slots
{
    const int sub  = blockIdx.x;           // 0..7
    const int tid  = threadIdx.x;
    const int lane = tid & 63;
    const int wv   = tid >> 6;             // wave 0..7
    const int dsel = tid >> 8;             // 0: dir0 threads, 1: dir1 threads
    const int tl   = tid & 255;            // local id within dir group
    const int kh   = tl >> 7;              // k-half 0/1 (wave-uniform)
    const int lrow = tl & 127;             // local gate row 0..127
    const int R    = (lrow >> 5) * 256 + sub * 32 + (lrow & 31); // global row

    const float* __restrict__ xw  = dsel ? xw_b : xw_f;
    const float* __restrict__ Whh = dsel ? Whh_b : Whh_f;
    const float4* __restrict__ Wr =
        (const float4*)(Whh + (size_t)R * 256 + (kh << 7));

    __shared__ float h0_sh[256], h1_sh[256];
    __shared__ float part0[256], part1[256];
    float* __restrict__ h_sh  = dsel ? h1_sh : h0_sh;
    float* __restrict__ partd = dsel ? part1 : part0;

    const bool isProd = (wv == 0 || wv == 4) && lane < 32;
    float c = 0.f;                         // carry, live in producer lanes
    if (tid < 256) { h0_sh[tid] = 0.f; h1_sh[tid] = 0.f; }   // h_0 = 0
    __syncthreads();

    for (int t = 0; t < 1024; t++) {
        const int trow = dsel ? (1023 - t) : t;

        // ---- producer: issue this step's 4 xw loads (land during dot) ----
        float xg0 = 0.f, xg1 = 0.f, xg2 = 0.f, xg3 = 0.f;
        if (isProd) {
            const float* xr = &xw[(size_t)trow * 1024 + sub * 32 + lane];
            xg0 = xr[0];   xg1 = xr[256];
            xg2 = xr[512]; xg3 = xr[768];
        }

        // ---- phase 1: 64-MAC dot over this thread's k-half (both dirs) ----
        float a0 = 0.f, a1 = 0.f, a2 = 0.f, a3 = 0.f;
        const float4* hp4 = (const float4*)&h_sh[kh << 7];   // bcast reads
#pragma unroll
        for (int i = 0; i < 16; i += 4) {
            float4 h0v = hp4[i + 0], w0v = Wr[i + 0];
            float4 h1v = hp4[i + 1], w1v = Wr[i + 1];
            float4 h2v = hp4[i + 2], w2v = Wr[i + 2];
            float4 h3v = hp4[i + 3], w3v = Wr[i + 3];
            a0 += w0v.x * h0v.x + w0v.y * h0v.y + w0v.z * h0v.z + w0v.w * h0v.w;
            a1 += w1v.x * h1v.x + w1v.y * h1v.y + w1v.z * h1v.z + w1v.w * h1v.w;
            a2 += w2v.x * h2v.x + w2v.y * h2v.y + w2v.z * h2v.z + w2v.w * h2v.w;
            a3 += w3v.x * h3v.x + w3v.y * h3v.y + w3v.z * h3v.z + w3v.w * h3v.w;
        }
        partd[tl] = (a0 + a1) + (a2 + a3);
        __syncthreads();                                     // B1

        // ---- phase 2: producers finish gates+c/h+publish; others poll ----
        const int par = (t + 1) & 1;
        if (isProd) {
            float s0 = partd[lane]      + partd[128 + lane]  + xg0;
            float s1 = partd[32 + lane] + partd[160 + lane]  + xg1;
            float s2 = partd[64 + lane] + partd[192 + lane]  + xg2;
            float s3 = partd[96 + lane] + partd[224 + lane]  + xg3;
            float iv = sigm_f(s0), fv = sigm_f(s1);
            float gv = tanh_f(s2), ov = sigm_f(s3);
            c = fv * c + iv * gv;
            float h = ov * tanh_f(c);
            if (t + 1 < 1024) {
                unsigned long long msg =
                    ((unsigned long long)(unsigned)(t + 1) << 32) |
                    (unsigned long long)__float_as_uint(h);
                st_msg(&hx[(((sub << 1) + par) << 6) + (dsel << 5) + lane], msg);
                h_sh[sub * 32 + lane] = h;       // own chunk via LDS
            }
            hout[(size_t)trow * 512 + (dsel << 8) + sub * 32 + lane] = h;
        }
        if (wv != 0 && t + 1 < 1024) {
            int pw = (sub + wv) & 7;          // producer block this wave tracks
            const unsigned long long* sp =
                &hx[(((pw << 1) + par) << 6) + lane];        // both dir halves
            unsigned long long v = poll_msg(sp, (unsigned)(t + 1));
            float hv = __uint_as_float((unsigned)v);
            ((lane < 32) ? h0_sh : h1_sh)[pw * 32 + (lane & 31)] = hv;
        }
        __syncthreads();                                     // B2
    }
}

// ------------------------- transpose mlp_W1 ---------------------------------
__global__ __launch_bounds__(256) void transpose_w1(
    const float* __restrict__ W1, float* __restrict__ W1T)
{
    int idx = blockIdx.x * 256 + threadIdx.x;
    if (idx >= 100 * 1024) return;
    int n = idx / 1024, j = idx % 1024;
    W1T[j * 100 + n] = W1[idx];
}

// ---------------------- A = h1 Wh^T + b1, B = h1 Wm^T -----------------------
__global__ __launch_bounds__(256) void ab_kernel(
    const float* __restrict__ h1, const float* __restrict__ W1T,
    const float* __restrict__ b1v,
    float* __restrict__ Ab, float* __restrict__ Bb)
{
    int m0 = blockIdx.x * 16;
    __shared__ float hs[16][512];
    int tid = threadIdx.x;
    for (int idx = tid * 4; idx < 16 * 512; idx += 1024) {
        int r = idx >> 9, cc = idx & 511;
        *(float4*)&hs[r][cc] = *(const float4*)&h1[(size_t)(m0 + r) * 512 + cc];
    }
    __syncthreads();
    bool isB = tid >= 128;
    int n = tid & 127;
    if (n < 100) {
        float acc[16] = {};
        const float* wbase = W1T + (isB ? 512 * 100 : 0) + n;
#pragma unroll 4
        for (int k = 0; k < 512; k++) {
            float wv = wbase[k * 100];
#pragma unroll
            for (int m = 0; m < 16; m++) acc[m] += hs[m][k] * wv;
        }
        float badd = isB ? 0.f : b1v[n];
        float* dst = isB ? Bb : Ab;
#pragma unroll
        for (int m = 0; m < 16; m++) dst[(m0 + m) * 100 + n] = acc[m] + badd;
    }
}

// ------------------------------ pair MLP ------------------------------------
__global__ __launch_bounds__(256) void pair_kernel(
    const float* __restrict__ Ab, const float* __restrict__ Bb,
    const float* __restrict__ W2, const float* __restrict__ b2,
    float* __restrict__ sT)
{
    int i0 = blockIdx.x * 32, j0 = blockIdx.y * 32;
    __shared__ float Ash[32][101];
    __shared__ float Bsh[32][101];
    __shared__ float w2s[100];
    int tid = threadIdx.x;
    for (int idx = tid; idx < 3200; idx += 256) {
        int r = idx / 100, cc = idx % 100;
        Ash[r][cc] = Ab[(i0 + r) * 100 + cc];
        Bsh[r][cc] = Bb[(j0 + r) * 100 + cc];
    }
    if (tid < 100) w2s[tid] = W2[tid];
    __syncthreads();
    float b2v = b2[0];
    int il = (tid & 15) * 2, jl = (tid >> 4) * 2;
    float a00 = 0.f, a01 = 0.f, a10 = 0.f, a11 = 0.f;
#pragma unroll 4
    for (int k = 0; k < 100; k++) {
        float wv = w2s[k];
        float x0 = Ash[il][k], x1 = Ash[il + 1][k];
        float y0 = Bsh[jl][k], y1 = Bsh[jl + 1][k];
        a00 += wv * tanh_f(x0 + y0);
        a01 += wv * tanh_f(x0 + y1);
        a10 += wv * tanh_f(x1 + y0);
        a11 += wv * tanh_f(x1 + y1);
    }
    float vals[2][2] = {{a00, a01}, {a10, a11}};
#pragma unroll
    for (int a = 0; a < 2; a++)
#pragma unroll
        for (int b = 0; b < 2; b++) {
            int gi2 = i0 + il + a, gj = j0 + jl + b;
            float v = vals[a][b] + b2v;
            if (gi2 == gj) v = 0.f;
            sT[(size_t)gj * 1024 + gi2] = v;
        }
}

// ------------------------- column stats (softmax) ---------------------------
__global__ __launch_bounds__(256) void colstats(
    const float* __restrict__ sT, float* __restrict__ mx, float* __restrict__ rs)
{
    int j = blockIdx.x;
    const float* row = sT + (size_t)j * 1024;
    int tid = threadIdx.x;
    __shared__ float red[256];
    float m = -INFINITY;
    for (int i = tid; i < 1024; i += 256) m = fmaxf(m, row[i]);
    red[tid] = m; __syncthreads();
    for (int s = 128; s > 0; s >>= 1) {
        if (tid < s) red[tid] = fmaxf(red[tid], red[tid + s]);
        __syncthreads();
    }
    float mxv = red[0];
    __syncthreads();
    float ssum = 0.f;
    for (int i = tid; i < 1024; i += 256) ssum += exp2f((row[i] - mxv) * L2E);
    red[tid] = ssum; __syncthreads();
    for (int s = 128; s > 0; s >>= 1) {
        if (tid < s) red[tid] += red[tid + s];
        __syncthreads();
    }
    if (tid == 0) { mx[j] = mxv; rs[j] = 1.f / red[0]; }
}

// ----------------------- normalize + transpose write ------------------------
__global__ __launch_bounds__(256) void writeout(
    const float* __restrict__ sT, const float* __restrict__ mx,
    const float* __restrict__ rs, float* __restrict__ out)
{
    int i0 = blockIdx.x * 32, j0 = blockIdx.y * 32;
    __shared__ float til[32][33];
    int tid = threadIdx.x;
    int r = tid >> 3, c4 = (tid & 7) * 4;
    float4 v = *(const float4*)&sT[(size_t)(j0 + r) * 1024 + i0 + c4];
    til[r][c4 + 0] = v.x; til[r][c4 + 1] = v.y;
    til[r][c4 + 2] = v.z; til[r][c4 + 3] = v.w;
    __syncthreads();
    float4 o;
    float* op = &out[(size_t)(i0 + r) * 1024 + j0 + c4];
    o.x = exp2f((til[c4 + 0][r] - mx[j0 + c4 + 0]) * L2E) * rs[j0 + c4 + 0];
    o.y = exp2f((til[c4 + 1][r] - mx[j0 + c4 + 1]) * L2E) * rs[j0 + c4 + 1];
    o.z = exp2f((til[c4 + 2][r] - mx[j0 + c4 + 2]) * L2E) * rs[j0 + c4 + 2];
    o.w = exp2f((til[c4 + 3][r] - mx[j0 + c4 + 3]) * L2E) * rs[j0 + c4 + 3];
    *(float4*)op = o;
}

// ---------------------------------------------------------------------------
extern "C" void kernel_launch(void* const* d_in, const int* in_sizes, int n_in,
                              void* d_out, int out_size, void* d_ws, size_t ws_size,
                              hipStream_t stream)
{
    const float* word_table = (const float*)d_in[0];
    const float* pos_table  = (const float*)d_in[1];
    const float* l0f_Wih = (const float*)d_in[2];
    const float* l0f_Whh = (const float*)d_in[3];
    const float* l0f_b   = (const float*)d_in[4];
    const float* l0b_Wih = (const float*)d_in[5];
    const float* l0b_Whh = (const float*)d_in[6];
    const float* l0b_b   = (const float*)d_in[7];
    const float* l1f_Wih = (const float*)d_in[8];
    const float* l1f_Whh = (const float*)d_in[9];
    const float* l1f_b   = (const float*)d_in[10];
    const float* l1b_Wih = (const float*)d_in[11];
    const float* l1b_Whh = (const float*)d_in[12];
    const float* l1b_b   = (const float*)d_in[13];
    const float* mlp_W1  = (const float*)d_in[14];
    const float* mlp_b1  = (const float*)d_in[15];
    const float* mlp_W2  = (const float*)d_in[16];
    const float* mlp_b2  = (const float*)d_in[17];
    const int*   word_idx = (const int*)d_in[18];
    const int*   pos_idx  = (const int*)d_in[19];
    float* out = (float*)d_out;

    float* ws = (float*)d_ws;
    const size_t OFF_X   = 0;            // 1024*576
    const size_t OFF_XWF = 589824;       // 1024*1024
    const size_t OFF_XWB = 1638400;      // 1024*1024
    const size_t OFF_H0  = 2686976;      // 1024*512
    const size_t OFF_H1  = 3211264;      // 1024*512
    const size_t OFF_W1T = 3735552;      // 1024*100
    const size_t OFF_A   = 3837952;      // 1024*100
    const size_t OFF_B   = 3940352;      // 1024*100
    const size_t OFF_ST  = 4042752;      // 1024*1024
    const size_t OFF_MX  = 5091328;      // 1024
    const size_t OFF_RS  = 5092352;      // 1024
    const size_t OFF_HX  = 5095424;      // 2 scans * 1024 u64 (= 4096 floats)

    float* x   = ws + OFF_X;
    float* xwf = ws + OFF_XWF;
    float* xwb = ws + OFF_XWB;
    float* h0  = ws + OFF_H0;
    float* h1  = ws + OFF_H1;
    float* w1t = ws + OFF_W1T;
    float* Ab  = ws + OFF_A;
    float* Bb  = ws + OFF_B;
    float* sT  = ws + OFF_ST;
    float* mx  = ws + OFF_MX;
    float* rs  = ws + OFF_RS;
    unsigned long long* hx0 = (unsigned long long*)(ws + OFF_HX);
    unsigned long long* hx1 = hx0 + 1024;

    // zero tagged slots so replays never consume stale tags
    hipMemsetAsync(hx0, 0, 2048 * sizeof(unsigned long long), stream);

    embed_kernel<<<(1024 * 576 + 255) / 256, 256, 0, stream>>>(
        word_table, pos_table, word_idx, pos_idx, x);

    transpose_w1<<<(100 * 1024 + 255) / 256, 256, 0, stream>>>(mlp_W1, w1t);

    gemm_bias<<<dim3(16, 16, 2), 256, 0, stream>>>(
        x, l0f_Wih, l0b_Wih, l0f_b, l0b_b, xwf, xwb, 1024, 1024, 576);

    lstm_scan<<<8, 512, 0, stream>>>(
        xwf, xwb, l0f_Whh, l0b_Whh, h0, hx0);

    gemm_bias<<<dim3(16, 16, 2), 256, 0, stream>>>(
        h0, l1f_Wih, l1b_Wih, l1f_b, l1b_b, xwf, xwb, 1024, 1024, 512);

    lstm_scan<<<8, 512, 0, stream>>>(
        xwf, xwb, l1f_Whh, l1b_Whh, h1, hx1);

    ab_kernel<<<64, 256, 0, stream>>>(h1, w1t, mlp_b1, Ab, Bb);

    pair_kernel<<<dim3(32, 32), 256, 0, stream>>>(Ab, Bb, mlp_W2, mlp_b2, sT);

    colstats<<<1024, 256, 0, stream>>>(sT, mx, rs);

    writeout<<<dim3(32, 32), 256, 0, stream>>>(sT, mx, rs, out);
}

// Round 13
// 3664.507 us; speedup vs baseline: 1.1179x; 1.1179x over previous
//
#include <hip/hip_runtime.h>
#include <hip/hip_bf16.h>

// ---------------------------------------------------------------------------
// KiperwasserDependencyParser: embed -> bi-LSTM x2 -> pairwise MLP -> softmax
// Round 13: 16 dual-dir scan blocks; 64 weight f32/thread (16 float4,
// R7-proven register-resident) -> no steady-state weight traffic.
// Fused tag|h messages, 15-slot poll map, 2 barriers/step.
// ---------------------------------------------------------------------------

#define L2E 1.4426950408889634f

__device__ __forceinline__ float fast_rcp(float x) { return __builtin_amdgcn_rcpf(x); }
__device__ __forceinline__ float sigm_f(float x) {
    return fast_rcp(1.f + exp2f(-x * L2E));
}
__device__ __forceinline__ float tanh_f(float x) {
    return 1.f - 2.f * fast_rcp(1.f + exp2f(x * (2.f * L2E)));
}

// publish tagged 8B message to the coherence point (R10/R11-proven).
__device__ __forceinline__ void st_msg(unsigned long long* p, unsigned long long m) {
    asm volatile("global_store_dwordx2 %0, %1, off sc0 sc1"
                 :: "v"(p), "v"(m) : "memory");
}

// 4-deep pipelined poll (R10-proven); bounded, falls back to the proven
// relaxed-agent loop. __all is over ACTIVE lanes (divergence-safe).
__device__ __forceinline__ unsigned long long poll_msg(
    const unsigned long long* p, unsigned want)
{
    unsigned long long r0, r1, r2, r3, r = 0;
    bool done = false;
    for (int it = 0; it < 8192 && !done; ++it) {
        asm volatile(
            "global_load_dwordx2 %0, %4, off sc0 sc1\n\t"
            "global_load_dwordx2 %1, %4, off sc0 sc1\n\t"
            "global_load_dwordx2 %2, %4, off sc0 sc1\n\t"
            "global_load_dwordx2 %3, %4, off sc0 sc1\n\t"
            "s_waitcnt vmcnt(3)"
            : "=&v"(r0), "=&v"(r1), "=&v"(r2), "=&v"(r3)
            : "v"(p) : "memory");
        if (__all((unsigned)(r0 >> 32) == want)) { r = r0; done = true; }
        if (!done) {
            asm volatile("s_waitcnt vmcnt(2)" ::: "memory");
            if (__all((unsigned)(r1 >> 32) == want)) { r = r1; done = true; }
        }
        if (!done) {
            asm volatile("s_waitcnt vmcnt(1)" ::: "memory");
            if (__all((unsigned)(r2 >> 32) == want)) { r = r2; done = true; }
        }
        if (!done) {
            asm volatile("s_waitcnt vmcnt(0)" ::: "memory");
            if (__all((unsigned)(r3 >> 32) == want)) { r = r3; done = true; }
        }
        asm volatile("s_waitcnt vmcnt(0)" ::: "memory");
    }
    if (!done) {
        do {
            r = __hip_atomic_load(p, __ATOMIC_RELAXED, __HIP_MEMORY_SCOPE_AGENT);
        } while (!__all((unsigned)(r >> 32) == want));
    }
    return r;
}

// ----------------------------- embed ---------------------------------------
__global__ __launch_bounds__(256) void embed_kernel(
    const float* __restrict__ wt, const float* __restrict__ pt,
    const int* __restrict__ wi, const int* __restrict__ pi,
    float* __restrict__ x)
{
    int idx = blockIdx.x * 256 + threadIdx.x;
    if (idx >= 1024 * 576) return;
    int n = idx / 576, c = idx % 576;
    x[idx] = (c < 512) ? wt[wi[n] * 512 + c] : pt[pi[n] * 64 + (c - 512)];
}

// --------------------------- GEMM + bias ------------------------------------
__global__ __launch_bounds__(256) void gemm_bias(
    const float* __restrict__ A,
    const float* __restrict__ W0, const float* __restrict__ W1,
    const float* __restrict__ b0, const float* __restrict__ b1,
    float* __restrict__ C0, float* __restrict__ C1,
    int M, int N, int K)
{
    const float* W = blockIdx.z ? W1 : W0;
    const float* bias = blockIdx.z ? b1 : b0;
    float* C = blockIdx.z ? C1 : C0;
    int m0 = blockIdx.y * 64, n0 = blockIdx.x * 64;
    __shared__ float As[16][65];
    __shared__ float Ws[16][65];
    int tid = threadIdx.x;
    int tx = tid & 15, ty = tid >> 4;
    float acc[4][4] = {};
    int lr = tid >> 2, lkc = (tid & 3) * 4;
    for (int k0 = 0; k0 < K; k0 += 16) {
        float4 a4 = *(const float4*)&A[(size_t)(m0 + lr) * K + k0 + lkc];
        float4 w4 = *(const float4*)&W[(size_t)(n0 + lr) * K + k0 + lkc];
        As[lkc + 0][lr] = a4.x; As[lkc + 1][lr] = a4.y;
        As[lkc + 2][lr] = a4.z; As[lkc + 3][lr] = a4.w;
        Ws[lkc + 0][lr] = w4.x; Ws[lkc + 1][lr] = w4.y;
        Ws[lkc + 2][lr] = w4.z; Ws[lkc + 3][lr] = w4.w;
        __syncthreads();
#pragma unroll
        for (int k = 0; k < 16; k++) {
            float a[4], b[4];
#pragma unroll
            for (int i = 0; i < 4; i++) a[i] = As[k][ty * 4 + i];
#pragma unroll
            for (int j = 0; j < 4; j++) b[j] = Ws[k][tx * 4 + j];
#pragma unroll
            for (int i = 0; i < 4; i++)
#pragma unroll
                for (int j = 0; j < 4; j++) acc[i][j] += a[i] * b[j];
        }
        __syncthreads();
    }
    int colbase = n0 + tx * 4;
    float4 bv = *(const float4*)&bias[colbase];
#pragma unroll
    for (int i = 0; i < 4; i++) {
        float4 o;
        o.x = acc[i][0] + bv.x; o.y = acc[i][1] + bv.y;
        o.z = acc[i][2] + bv.z; o.w = acc[i][3] + bv.w;
        *(float4*)&C[(size_t)(m0 + ty * 4 + i) * N + colbase] = o;
    }
}

// ----------------------------- LSTM scan ------------------------------------
// 16 blocks; block `sub` owns h[16*sub..16*sub+16) of BOTH directions.
// Threads 0-255 dot dir0, 256-511 dot dir1. Per dir: 64 gate rows x 4
// k-quarters -> 64 weight f32/thread = 16 float4 REGISTERS (R7-proven
// residency at launch_bounds(512,2)). Producers: wave 0 lanes 0-15 (dir0),
// 16-31 (dir1). Message slots [prod 16][par 2][32]: lanes 0-15 dir0 h,
// 16-31 dir1 h. Poll map: wave0 lanes 32-63 -> prod sub+8; waves 1-7
// lanes 0-31 -> sub+w, lanes 32-63 -> sub+w+8. 2 barriers/step.
__global__ __launch_bounds__(512, 2) void lstm_scan(
    const float* __restrict__ xw_f, const float* __restrict__ xw_b,
    const float* __restrict__ Whh_f, const float* __restrict__ Whh_b,
    float* __restrict__ hout,              // [1024][512]
    unsigned long long* __restrict__ hx)   // [prod 16][par 2][32] slots
{
    const int sub  = blockIdx.x;           // 0..15
    const int tid  = threadIdx.x;
    const int lane = tid & 63;
    const int wv   = tid >> 6;             // wave 0..7
    const int dsel = tid >> 8;             // 0: dir0 dot, 1: dir1 dot
    const int tl   = tid & 255;            // local id within dir group
    const int q    = tl >> 6;              // k-quarter 0..3 (wave-uniform)
    const int lr   = tl & 63;              // gate row 0..63
    const int R    = (lr >> 4) * 256 + sub * 16 + (lr & 15); // global row

    const float* __restrict__ Whh = dsel ? Whh_b : Whh_f;

    // ---- 64 weight f32 -> 16 float4 registers (R7-proven resident) ----
    float4 w4[16];
    {
        const float4* Wr = (const float4*)(Whh + (size_t)R * 256 + (q << 6));
#pragma unroll
        for (int i = 0; i < 16; i++) w4[i] = Wr[i];
    }

    __shared__ float h0_sh[256], h1_sh[256];
    __shared__ float part0[256], part1[256];
    float* __restrict__ h_shd = dsel ? h1_sh : h0_sh;
    float* __restrict__ partd = dsel ? part1 : part0;

    const bool isProd = (wv == 0) && (lane < 32);
    float c = 0.f;                         // carry in producer lanes
    if (tid < 256) { h0_sh[tid] = 0.f; h1_sh[tid] = 0.f; }   // h_0 = 0
    __syncthreads();

    for (int t = 0; t < 1024; t++) {
        // ---- producer: issue this step's 4 xw loads (land during dot) ----
        float xg0 = 0.f, xg1 = 0.f, xg2 = 0.f, xg3 = 0.f;
        if (isProd) {
            int pd = lane >> 4, hid = lane & 15;
            int trp = pd ? (1023 - t) : t;
            const float* xr = (pd ? xw_b : xw_f) +
                              (size_t)trp * 1024 + sub * 16 + hid;
            xg0 = xr[0];   xg1 = xr[256];
            xg2 = xr[512]; xg3 = xr[768];
        }

        // ---- phase 1: 64-MAC register dot (h broadcast from LDS) ----
        float a0 = 0.f, a1 = 0.f, a2 = 0.f, a3 = 0.f;
        const float4* hp4 = (const float4*)&h_shd[q << 6];
#pragma unroll
        for (int i = 0; i < 16; i += 4) {
            float4 h0v = hp4[i + 0], h1v = hp4[i + 1];
            float4 h2v = hp4[i + 2], h3v = hp4[i + 3];
            a0 += w4[i+0].x*h0v.x + w4[i+0].y*h0v.y + w4[i+0].z*h0v.z + w4[i+0].w*h0v.w;
            a1 += w4[i+1].x*h1v.x + w4[i+1].y*h1v.y + w4[i+1].z*h1v.z + w4[i+1].w*h1v.w;
            a2 += w4[i+2].x*h2v.x + w4[i+2].y*h2v.y + w4[i+2].z*h2v.z + w4[i+2].w*h2v.w;
            a3 += w4[i+3].x*h3v.x + w4[i+3].y*h3v.y + w4[i+3].z*h3v.z + w4[i+3].w*h3v.w;
        }
        partd[tl] = (a0 + a1) + (a2 + a3);
        __syncthreads();                                     // B1

        // ---- phase 2: producers gates+c/h+publish | others poll ----
        const int par = (t + 1) & 1;
        if (isProd) {
            int pd = lane >> 4, hid = lane & 15;
            const float* pp = pd ? part1 : part0;
            float s0 = pp[hid]       + pp[64 + hid]  + pp[128 + hid]  + pp[192 + hid]  + xg0;
            float s1 = pp[16 + hid]  + pp[80 + hid]  + pp[144 + hid]  + pp[208 + hid]  + xg1;
            float s2 = pp[32 + hid]  + pp[96 + hid]  + pp[160 + hid]  + pp[224 + hid]  + xg2;
            float s3 = pp[48 + hid]  + pp[112 + hid] + pp[176 + hid]  + pp[240 + hid]  + xg3;
            float iv = sigm_f(s0), fv = sigm_f(s1);
            float gv = tanh_f(s2), ov = sigm_f(s3);
            c = fv * c + iv * gv;
            float h = ov * tanh_f(c);
            if (t + 1 < 1024) {
                unsigned long long msg =
                    ((unsigned long long)(unsigned)(t + 1) << 32) |
                    (unsigned long long)__float_as_uint(h);
                st_msg(&hx[(((sub << 1) + par) << 5) + lane], msg);
                (pd ? h1_sh : h0_sh)[sub * 16 + hid] = h;    // own chunk via LDS
            }
            int trp = pd ? (1023 - t) : t;
            hout[(size_t)trp * 512 + (pd << 8) + sub * 16 + hid] = h;
        }
        if (t + 1 < 1024 && (wv != 0 || lane >= 32)) {
            int pw = (wv == 0) ? ((sub + 8) & 15)
                               : ((lane < 32) ? ((sub + wv) & 15)
                                              : ((sub + wv + 8) & 15));
            const unsigned long long* sp =
                &hx[(((pw << 1) + par) << 5) + (lane & 31)];
            unsigned long long v = poll_msg(sp, (unsigned)(t + 1));
            float hv = __uint_as_float((unsigned)v);
            int hl = lane & 31;
            ((hl < 16) ? h0_sh : h1_sh)[pw * 16 + (hl & 15)] = hv;
        }
        __syncthreads();                                     // B2

        // keep weights register-resident (scalar ties)
#pragma unroll
        for (int i = 0; i < 16; i++)
            asm volatile("" : "+v"(w4[i].x), "+v"(w4[i].y),
                              "+v"(w4[i].z), "+v"(w4[i].w));
    }
}

// ------------------------- transpose mlp_W1 ---------------------------------
__global__ __launch_bounds__(256) void transpose_w1(
    const float* __restrict__ W1, float* __restrict__ W1T)
{
    int idx = blockIdx.x * 256 + threadIdx.x;
    if (idx >= 100 * 1024) return;
    int n = idx / 1024, j = idx % 1024;
    W1T[j * 100 + n] = W1[idx];
}

// ---------------------- A = h1 Wh^T + b1, B = h1 Wm^T -----------------------
__global__ __launch_bounds__(256) void ab_kernel(
    const float* __restrict__ h1, const float* __restrict__ W1T,
    const float* __restrict__ b1v,
    float* __restrict__ Ab, float* __restrict__ Bb)
{
    int m0 = blockIdx.x * 16;
    __shared__ float hs[16][512];
    int tid = threadIdx.x;
    for (int idx = tid * 4; idx < 16 * 512; idx += 1024) {
        int r = idx >> 9, cc = idx & 511;
        *(float4*)&hs[r][cc] = *(const float4*)&h1[(size_t)(m0 + r) * 512 + cc];
    }
    __syncthreads();
    bool isB = tid >= 128;
    int n = tid & 127;
    if (n < 100) {
        float acc[16] = {};
        const float* wbase = W1T + (isB ? 512 * 100 : 0) + n;
#pragma unroll 4
        for (int k = 0; k < 512; k++) {
            float wv = wbase[k * 100];
#pragma unroll
            for (int m = 0; m < 16; m++) acc[m] += hs[m][k] * wv;
        }
        float badd = isB ? 0.f : b1v[n];
        float* dst = isB ? Bb : Ab;
#pragma unroll
        for (int m = 0; m < 16; m++) dst[(m0 + m) * 100 + n] = acc[m] + badd;
    }
}

// ------------------------------ pair MLP ------------------------------------
__global__ __launch_bounds__(256) void pair_kernel(
    const float* __restrict__ Ab, const float* __restrict__ Bb,
    const float* __restrict__ W2, const float* __restrict__ b2,
    float* __restrict__ sT)
{
    int i0 = blockIdx.x * 32, j0 = blockIdx.y * 32;
    __shared__ float Ash[32][101];
    __shared__ float Bsh[32][101];
    __shared__ float w2s[100];
    int tid = threadIdx.x;
    for (int idx = tid; idx < 3200; idx += 256) {
        int r = idx / 100, cc = idx % 100;
        Ash[r][cc] = Ab[(i0 + r) * 100 + cc];
        Bsh[r][cc] = Bb[(j0 + r) * 100 + cc];
    }
    if (tid < 100) w2s[tid] = W2[tid];
    __syncthreads();
    float b2v = b2[0];
    int il = (tid & 15) * 2, jl = (tid >> 4) * 2;
    float a00 = 0.f, a01 = 0.f, a10 = 0.f, a11 = 0.f;
#pragma unroll 4
    for (int k = 0; k < 100; k++) {
        float wv = w2s[k];
        float x0 = Ash[il][k], x1 = Ash[il + 1][k];
        float y0 = Bsh[jl][k], y1 = Bsh[jl + 1][k];
        a00 += wv * tanh_f(x0 + y0);
        a01 += wv * tanh_f(x0 + y1);
        a10 += wv * tanh_f(x1 + y0);
        a11 += wv * tanh_f(x1 + y1);
    }
    float vals[2][2] = {{a00, a01}, {a10, a11}};
#pragma unroll
    for (int a = 0; a < 2; a++)
#pragma unroll
        for (int b = 0; b < 2; b++) {
            int gi2 = i0 + il + a, gj = j0 + jl + b;
            float v = vals[a][b] + b2v;
            if (gi2 == gj) v = 0.f;
            sT[(size_t)gj * 1024 + gi2] = v;
        }
}

// ------------------------- column stats (softmax) ---------------------------
__global__ __launch_bounds__(256) void colstats(
    const float* __restrict__ sT, float* __restrict__ mx, float* __restrict__ rs)
{
    int j = blockIdx.x;
    const float* row = sT + (size_t)j * 1024;
    int tid = threadIdx.x;
    __shared__ float red[256];
    float m = -INFINITY;
    for (int i = tid; i < 1024; i += 256) m = fmaxf(m, row[i]);
    red[tid] = m; __syncthreads();
    for (int s = 128; s > 0; s >>= 1) {
        if (tid < s) red[tid] = fmaxf(red[tid], red[tid + s]);
        __syncthreads();
    }
    float mxv = red[0];
    __syncthreads();
    float ssum = 0.f;
    for (int i = tid; i < 1024; i += 256) ssum += exp2f((row[i] - mxv) * L2E);
    red[tid] = ssum; __syncthreads();
    for (int s = 128; s > 0; s >>= 1) {
        if (tid < s) red[tid] += red[tid + s];
        __syncthreads();
    }
    if (tid == 0) { mx[j] = mxv; rs[j] = 1.f / red[0]; }
}

// ----------------------- normalize + transpose write ------------------------
__global__ __launch_bounds__(256) void writeout(
    const float* __restrict__ sT, const float* __restrict__ mx,
    const float* __restrict__ rs, float* __restrict__ out)
{
    int i0 = blockIdx.x * 32, j0 = blockIdx.y * 32;
    __shared__ float til[32][33];
    int tid = threadIdx.x;
    int r = tid >> 3, c4 = (tid & 7) * 4;
    float4 v = *(const float4*)&sT[(size_t)(j0 + r) * 1024 + i0 + c4];
    til[r][c4 + 0] = v.x; til[r][c4 + 1] = v.y;
    til[r][c4 + 2] = v.z; til[r][c4 + 3] = v.w;
    __syncthreads();
    float4 o;
    float* op = &out[(size_t)(i0 + r) * 1024 + j0 + c4];
    o.x = exp2f((til[c4 + 0][r] - mx[j0 + c4 + 0]) * L2E) * rs[j0 + c4 + 0];
    o.y = exp2f((til[c4 + 1][r] - mx[j0 + c4 + 1]) * L2E) * rs[j0 + c4 + 1];
    o.z = exp2f((til[c4 + 2][r] - mx[j0 + c4 + 2]) * L2E) * rs[j0 + c4 + 2];
    o.w = exp2f((til[c4 + 3][r] - mx[j0 + c4 + 3]) * L2E) * rs[j0 + c4 + 3];
    *(float4*)op = o;
}

// ---------------------------------------------------------------------------
extern "C" void kernel_launch(void* const* d_in, const int* in_sizes, int n_in,
                              void* d_out, int out_size, void* d_ws, size_t ws_size,
                              hipStream_t stream)
{
    const float* word_table = (const float*)d_in[0];
    const float* pos_table  = (const float*)d_in[1];
    const float* l0f_Wih = (const float*)d_in[2];
    const float* l0f_Whh = (const float*)d_in[3];
    const float* l0f_b   = (const float*)d_in[4];
    const float* l0b_Wih = (const float*)d_in[5];
    const float* l0b_Whh = (const float*)d_in[6];
    const float* l0b_b   = (const float*)d_in[7];
    const float* l1f_Wih = (const float*)d_in[8];
    const float* l1f_Whh = (const float*)d_in[9];
    const float* l1f_b   = (const float*)d_in[10];
    const float* l1b_Wih = (const float*)d_in[11];
    const float* l1b_Whh = (const float*)d_in[12];
    const float* l1b_b   = (const float*)d_in[13];
    const float* mlp_W1  = (const float*)d_in[14];
    const float* mlp_b1  = (const float*)d_in[15];
    const float* mlp_W2  = (const float*)d_in[16];
    const float* mlp_b2  = (const float*)d_in[17];
    const int*   word_idx = (const int*)d_in[18];
    const int*   pos_idx  = (const int*)d_in[19];
    float* out = (float*)d_out;

    float* ws = (float*)d_ws;
    const size_t OFF_X   = 0;            // 1024*576
    const size_t OFF_XWF = 589824;       // 1024*1024
    const size_t OFF_XWB = 1638400;      // 1024*1024
    const size_t OFF_H0  = 2686976;      // 1024*512
    const size_t OFF_H1  = 3211264;      // 1024*512
    const size_t OFF_W1T = 3735552;      // 1024*100
    const size_t OFF_A   = 3837952;      // 1024*100
    const size_t OFF_B   = 3940352;      // 1024*100
    const size_t OFF_ST  = 4042752;      // 1024*1024
    const size_t OFF_MX  = 5091328;      // 1024
    const size_t OFF_RS  = 5092352;      // 1024
    const size_t OFF_HX  = 5095424;      // 2 scans * 1024 u64 (= 4096 floats)

    float* x   = ws + OFF_X;
    float* xwf = ws + OFF_XWF;
    float* xwb = ws + OFF_XWB;
    float* h0  = ws + OFF_H0;
    float* h1  = ws + OFF_H1;
    float* w1t = ws + OFF_W1T;
    float* Ab  = ws + OFF_A;
    float* Bb  = ws + OFF_B;
    float* sT  = ws + OFF_ST;
    float* mx  = ws + OFF_MX;
    float* rs  = ws + OFF_RS;
    unsigned long long* hx0 = (unsigned long long*)(ws + OFF_HX);
    unsigned long long* hx1 = hx0 + 1024;

    // zero tagged slots so replays never consume stale tags
    hipMemsetAsync(hx0, 0, 2048 * sizeof(unsigned long long), stream);

    embed_kernel<<<(1024 * 576 + 255) / 256, 256, 0, stream>>>(
        word_table, pos_table, word_idx, pos_idx, x);

    transpose_w1<<<(100 * 1024 + 255) / 256, 256, 0, stream>>>(mlp_W1, w1t);

    gemm_bias<<<dim3(16, 16, 2), 256, 0, stream>>>(
        x, l0f_Wih, l0b_Wih, l0f_b, l0b_b, xwf, xwb, 1024, 1024, 576);

    lstm_scan<<<16, 512, 0, stream>>>(
        xwf, xwb, l0f_Whh, l0b_Whh, h0, hx0);

    gemm_bias<<<dim3(16, 16, 2), 256, 0, stream>>>(
        h0, l1f_Wih, l1b_Wih, l1f_b, l1b_b, xwf, xwb, 1024, 1024, 512);

    lstm_scan<<<16, 512, 0, stream>>>(
        xwf, xwb, l1f_Whh, l1b_Whh, h1, hx1);

    ab_kernel<<<64, 256, 0, stream>>>(h1, w1t, mlp_b1, Ab, Bb);

    pair_kernel<<<dim3(32, 32), 256, 0, stream>>>(Ab, Bb, mlp_W2, mlp_b2, sT);

    colstats<<<1024, 256, 0, stream>>>(sT, mx, rs);

    writeout<<<dim3(32, 32), 256, 0, stream>>>(sT, mx, rs, out);
}